// Round 3
// baseline (429.525 us; speedup 1.0000x reference)
//
#include <hip/hip_runtime.h>
#include <hip/hip_cooperative_groups.h>

namespace cg = cooperative_groups;

#define GXv 512
#define GYv 512
#define PMAX 32

constexpr int NB = 256;   // blocks — one per CU, guaranteed co-resident
constexpr int NT = 512;   // threads per block (8 waves)
constexpr int GT = NB * NT;  // 131072 total threads
// G = 524288 cells -> cells/block = 2048, cells/thread = 4 (int4 load)

typedef float vfloat4 __attribute__((ext_vector_type(4)));
typedef int   vint4   __attribute__((ext_vector_type(4)));

__global__ void __launch_bounds__(NT) mega_kernel(
        const float4* __restrict__ pts, const int* __restrict__ bidx,
        int* __restrict__ counts, int* __restrict__ lastp,
        float4* __restrict__ compact, int* __restrict__ agg,
        float4* __restrict__ out4, int N, int G) {
    cg::grid_group grid = cg::this_grid();
    const int t = threadIdx.x;
    const int b = blockIdx.x;
    const int gtid = b * NT + t;
    __shared__ int sm[NT];

    // ---- Phase 0: zero counts[G] + lastp[G] + compact[4G floats] = 6G ints ----
    {
        vint4* z = (vint4*)counts;   // counts,lastp,compact are contiguous in ws
        int n4 = (6 * G) / 4;
        vint4 zero4 = (vint4)0;
        for (int i = gtid; i < n4; i += GT) z[i] = zero4;
    }
    grid.sync();

    // ---- Phase 1: per-point binning: counts + last-write-wins position ----
    for (int i = gtid; i < N; i += GT) {
        float4 p = pts[i];
        // EXACT IEEE f32 division to match numpy (do NOT use * 5.0f)
        int x = (int)(p.x / 0.2f);
        int y = (int)(p.y / 0.2f);
        x = min(max(x, 0), GXv - 1);
        y = min(max(y, 0), GYv - 1);
        int flat = bidx[i] * (GXv * GYv) + x * GYv + y;
        atomicAdd(&counts[flat], 1);        // device scope
        atomicMax(&lastp[flat], i + 1);     // store pos+1, 0 == empty
    }
    grid.sync();

    // ---- Phase 2a: block-local occupied-count scan, publish block aggregate ----
    const int base = b * (NT * 4) + t * 4;          // 4 cells per thread
    int4 c4 = *(const int4*)&counts[base];
    int s = (c4.x > 0) + (c4.y > 0) + (c4.z > 0) + (c4.w > 0);
    sm[t] = s;
    __syncthreads();
    for (int off = 1; off < NT; off <<= 1) {
        int v = (t >= off) ? sm[t - off] : 0;
        __syncthreads();
        sm[t] += v;
        __syncthreads();
    }
    int excl = (t == 0) ? 0 : sm[t - 1];   // thread-exclusive within block
    if (t == 0) agg[b] = sm[NT - 1];
    grid.sync();

    // ---- Phase 2b: scan block aggregates, scatter winners into compact[rank] ----
    {
        int av = (t < NB) ? agg[t] : 0;
        sm[t] = av;
        __syncthreads();
        for (int off = 1; off < NT; off <<= 1) {
            int v = (t >= off) ? sm[t - off] : 0;
            __syncthreads();
            sm[t] += v;
            __syncthreads();
        }
        int blockBase = (b == 0) ? 0 : sm[b - 1];
        int rank = blockBase + excl;
        int cnt[4] = {c4.x, c4.y, c4.z, c4.w};
#pragma unroll
        for (int k = 0; k < 4; k++) {
            if (cnt[k] > 0) {
                if (cnt[k] <= PMAX) {
                    int p = lastp[base + k] - 1;   // last point of this pillar
                    compact[rank] = pts[p];
                }
                // over-full pillar: compact[rank] stays zero (pre-zeroed)
                rank++;
            }
        }
    }
    grid.sync();

    // ---- Phase 3: broadcast compact[j] over P=32 slots + zero counts output ----
    {
        const int total4 = G * PMAX;   // one float4 (C=4 floats) per (slot,p)
        const vfloat4* csrc = (const vfloat4*)compact;
        vfloat4* dst = (vfloat4*)out4;
        for (int idx = gtid; idx < total4; idx += GT) {
            vfloat4 v = csrc[idx >> 5];
            __builtin_nontemporal_store(v, &dst[idx]);
        }
        // voxel_counts: G int32 zeros right after the features
        vint4* outc4 = (vint4*)(out4 + (size_t)total4);
        int nc4 = G / 4;
        vint4 zero4 = (vint4)0;
        for (int i = gtid; i < nc4; i += GT) {
            __builtin_nontemporal_store(zero4, &outc4[i]);
        }
    }
}

extern "C" void kernel_launch(void* const* d_in, const int* in_sizes, int n_in,
                              void* d_out, int out_size, void* d_ws, size_t ws_size,
                              hipStream_t stream) {
    const float4* pts = (const float4*)d_in[0];
    const int* bidx = (const int*)d_in[1];
    int N = in_sizes[0] / 4;
    int G = out_size / 129;   // features G*32*4 + counts G

    // ws layout: counts[G] | lastp[G] | compact[G]{float4} | agg[NB]
    int* counts = (int*)d_ws;
    int* lastp = counts + G;
    float4* compact = (float4*)(lastp + G);
    int* agg = (int*)(compact + G);
    float4* out4 = (float4*)d_out;

    void* args[] = {(void*)&pts, (void*)&bidx, (void*)&counts, (void*)&lastp,
                    (void*)&compact, (void*)&agg, (void*)&out4, (void*)&N, (void*)&G};
    (void)hipLaunchCooperativeKernel(reinterpret_cast<void*>(mega_kernel),
                                     dim3(NB), dim3(NT), args, 0, stream);
}

// Round 4
// 318.637 us; speedup vs baseline: 1.3480x; 1.3480x over previous
//
#include <hip/hip_runtime.h>

#define GXv 512
#define GYv 512
#define PMAX 32

typedef float vfloat4 __attribute__((ext_vector_type(4)));
typedef int   vint4   __attribute__((ext_vector_type(4)));

// ---- K1: zero counts[G]+lastp[G] (ws) and the int32 counts output ----
__global__ void zero_kernel(vint4* __restrict__ ws, int na,
                            vint4* __restrict__ outc, int nc) {
    int i = blockIdx.x * blockDim.x + threadIdx.x;
    vint4 z = (vint4)0;
    if (i < na) ws[i] = z;
    if (i < nc) outc[i] = z;
}

// ---- K2: per-point binning: counts + last-write-wins position ----
__global__ void points_kernel(const float4* __restrict__ pts, const int* __restrict__ bidx,
                              int* __restrict__ counts, int* __restrict__ lastp, int N) {
    int i = blockIdx.x * blockDim.x + threadIdx.x;
    if (i >= N) return;
    float4 p = pts[i];
    // EXACT IEEE f32 division to match numpy (do NOT use * 5.0f)
    int x = (int)(p.x / 0.2f);
    int y = (int)(p.y / 0.2f);
    x = min(max(x, 0), GXv - 1);
    y = min(max(y, 0), GYv - 1);
    int flat = bidx[i] * (GXv * GYv) + x * GYv + y;
    atomicAdd(&counts[flat], 1);
    atomicMax(&lastp[flat], i + 1);   // pos+1, 0 == empty
}

// ---- K3: per-block occupied count (512 cells/block) ----
__global__ void blocksum_kernel(const int* __restrict__ counts, int* __restrict__ bs) {
    int t = threadIdx.x, b = blockIdx.x;
    int2 c = ((const int2*)counts)[b * 256 + t];
    __shared__ int sm[256];
    sm[t] = (c.x > 0) + (c.y > 0);
    __syncthreads();
    for (int off = 128; off > 0; off >>= 1) {
        if (t < off) sm[t] += sm[t + off];
        __syncthreads();
    }
    if (t == 0) bs[b] = sm[0];
}

// ---- K4: single-block exclusive scan of nb<=1024 block sums; bs[nb]=M total ----
__global__ void scan_kernel(int* __restrict__ bs, int nb) {
    __shared__ int sm[1024];
    int t = threadIdx.x;
    int v = (t < nb) ? bs[t] : 0;
    sm[t] = v;
    __syncthreads();
    for (int off = 1; off < 1024; off <<= 1) {
        int a = (t >= off) ? sm[t - off] : 0;
        __syncthreads();
        sm[t] += a;
        __syncthreads();
    }
    if (t < nb) bs[t] = (t == 0) ? 0 : sm[t - 1];
    if (t == nb - 1) bs[nb] = sm[t];   // M = total occupied
}

// ---- K5: fused rank + direct output write + tail zero ----
// 512 cells/block, 256 threads. Phase A: block scan for ranks.
// Phase B: each 32-lane half-wave writes one pillar's 32 slots (512 B coalesced).
// Phase C: grid-strided zero of slots [M, G).
__global__ __launch_bounds__(256) void scatter_kernel(
        const int* __restrict__ counts, const int* __restrict__ lastp,
        const int* __restrict__ bs, const vfloat4* __restrict__ pts,
        vfloat4* __restrict__ out, int G, int SB) {
    int t = threadIdx.x, b = blockIdx.x;
    int2 c2 = ((const int2*)counts)[b * 256 + t];
    int2 lp2 = ((const int2*)lastp)[b * 256 + t];
    int occ0 = (c2.x > 0), occ1 = (c2.y > 0);

    __shared__ int sm[256];
    __shared__ int enc[512];
    __shared__ int lpl[512];
    sm[t] = occ0 + occ1;
    __syncthreads();
    for (int off = 1; off < 256; off <<= 1) {
        int a = (t >= off) ? sm[t - off] : 0;
        __syncthreads();
        sm[t] += a;
        __syncthreads();
    }
    int excl = (t == 0) ? 0 : sm[t - 1];
    int r0 = bs[b] + excl;
    int r1 = r0 + occ0;
    // enc: -1 = unoccupied; else rank (bits 0..29) | overfull flag (bit 30)
    enc[2 * t]     = occ0 ? (r0 | ((c2.x > PMAX) ? (1 << 30) : 0)) : -1;
    enc[2 * t + 1] = occ1 ? (r1 | ((c2.y > PMAX) ? (1 << 30) : 0)) : -1;
    lpl[2 * t] = lp2.x;
    lpl[2 * t + 1] = lp2.y;
    __syncthreads();

    int w = t >> 6, lane = t & 63, half = lane >> 5, slot = lane & 31;
#pragma unroll 4
    for (int it = 0; it < 64; it++) {
        int cl = w * 128 + it * 2 + half;
        int e = enc[cl];
        if (e >= 0) {
            int rank = e & 0x3FFFFFFF;
            vfloat4 v = (vfloat4)0;
            if (!(e & (1 << 30))) v = pts[lpl[cl] - 1];  // 32 lanes same addr -> broadcast
            __builtin_nontemporal_store(v, &out[(size_t)rank * 32 + slot]);
        }
    }

    // Phase C: zero output slots [M, G)
    int M = bs[SB];
    size_t idx = (size_t)M * 32 + (size_t)b * 256 + t;
    size_t end = (size_t)G * 32;
    size_t stride = (size_t)SB * 256;
    vfloat4 z = (vfloat4)0;
    for (; idx < end; idx += stride)
        __builtin_nontemporal_store(z, &out[idx]);
}

extern "C" void kernel_launch(void* const* d_in, const int* in_sizes, int n_in,
                              void* d_out, int out_size, void* d_ws, size_t ws_size,
                              hipStream_t stream) {
    const float4* pts = (const float4*)d_in[0];
    const int* bidx = (const int*)d_in[1];
    int N = in_sizes[0] / 4;
    int G = out_size / 129;        // features G*32*4 floats + counts G ints
    int SB = G / 512;              // scatter/blocksum blocks (1024 for B=2)

    // ws: counts[G] | lastp[G] | bs[SB+1]
    int* counts = (int*)d_ws;
    int* lastp = counts + G;
    int* bs = lastp + G;
    vfloat4* out = (vfloat4*)d_out;
    vint4* outc = (vint4*)((float*)d_out + (size_t)G * (PMAX * 4));

    int na = (2 * G) / 4;          // counts+lastp as vint4
    int nc = G / 4;                // out counts as vint4
    zero_kernel<<<(na + 255) / 256, 256, 0, stream>>>((vint4*)d_ws, na, outc, nc);
    points_kernel<<<(N + 255) / 256, 256, 0, stream>>>(pts, bidx, counts, lastp, N);
    blocksum_kernel<<<SB, 256, 0, stream>>>(counts, bs);
    scan_kernel<<<1, 1024, 0, stream>>>(bs, SB);
    scatter_kernel<<<SB, 256, 0, stream>>>(counts, lastp, bs, (const vfloat4*)pts, out, G, SB);
}